// Round 9
// baseline (616.940 us; speedup 1.0000x reference)
//
#include <hip/hip_runtime.h>
#include <hip/hip_bf16.h>
#include <cstdint>
#include <cstddef>

#define I_      100
#define J_      8
#define D_IN    768
#define D_H     64
#define N_NODES 160000
#define N_HE    320000
#define N_INC   1600000
#define N_CELLS 800
#define VOCAB   30000

#define NRANGE   256
#define NPR      625
#define EPB      (N_INC / 256)

typedef unsigned short u16;
using short8 = __attribute__((ext_vector_type(8))) short;
using f32x4  = __attribute__((ext_vector_type(4))) float;

__device__ __forceinline__ float bf2f(u16 u) {
    union { uint32_t i; float f; } x; x.i = ((uint32_t)u) << 16; return x.f;
}
__device__ __forceinline__ u16 f2bf(float f) {
    union { float f; uint32_t i; } x; x.f = f;
    uint32_t b = x.i;
    b += 0x7FFFu + ((b >> 16) & 1u);
    return (u16)(b >> 16);
}
__device__ __forceinline__ float lo_bf(uint32_t u) {
    union { uint32_t i; float f; } x; x.i = u << 16; return x.f;
}
__device__ __forceinline__ float hi_bf(uint32_t u) {
    union { uint32_t i; float f; } x; x.i = u & 0xFFFF0000u; return x.f;
}
__device__ __forceinline__ uint32_t pack_bf2(float a, float b) {
    return (uint32_t)f2bf(a) | ((uint32_t)f2bf(b) << 16);
}

// grid-partition constants
#define G_OFF_HE   (N_INC / 256)        // 6250
#define G_OFF_CELL (N_NODES / 256)      // 625
#define G_CONV_BIG ((D_IN * 64) / 256)  // 192
#define G_CONV_SM  ((64 * 64) / 256)    // 16
#define G_KA       256
#define G_KC       256
#define G_KD       256
#define G_PGEMM    (VOCAB / 16)         // 1875 blocks (col-split: 4 waves = 16r x 4colblk)
#define G_XT       (N_NODES / 16)       // 10000 blocks
#define G_X0       ((I_ * J_) / 16)     // 50 blocks
#define G_HEDGE    (N_HE / 32)          // 10000 (8 hedges/wave)
#define G_NODE     (N_NODES / 32)       // 5000

// ---------------------------------------------------------------------------
__device__ __forceinline__ void dev_offsets(int bid, const int* __restrict__ sorted,
                                            int n, int nbins, int* __restrict__ off) {
    int i = bid * 256 + threadIdx.x;
    if (i >= n) return;
    int cur = sorted[i];
    int prev = (i == 0) ? -1 : sorted[i - 1];
    for (int b = prev + 1; b <= cur; ++b) off[b] = i;
    if (i == n - 1) {
        for (int b = cur + 1; b <= nbins; ++b) off[b] = n;
    }
}

__device__ __forceinline__ void dev_convT(int bid, const float* __restrict__ B,
                                          u16* __restrict__ Bt, int K) {
    int g = bid * 256 + threadIdx.x;
    if (g >= K * 64) return;
    int k = g >> 6, n = g & 63;
    Bt[(size_t)n * K + k] = f2bf(B[g]);
}

// ---------------------------------------------------------------------------
// bucket-sort CSR build
// ---------------------------------------------------------------------------
__device__ __forceinline__ void dev_ka(int bid, const int* __restrict__ inc_node,
                                       int* __restrict__ counts, int* __restrict__ lds) {
    int tid = threadIdx.x;
    lds[tid] = 0;
    __syncthreads();
    int s = bid * EPB, e = s + EPB;
    for (int i = s + tid; i < e; i += 256)
        atomicAdd(&lds[(unsigned)inc_node[i] / NPR], 1);
    __syncthreads();
    counts[bid * NRANGE + tid] = lds[tid];
}

__device__ __forceinline__ void dev_kb(const int* __restrict__ counts,
                                       int* __restrict__ chunk_off,
                                       int* __restrict__ range_base,
                                       int* __restrict__ lds) {
    int r = threadIdx.x;
    int run = 0;
    for (int b = 0; b < 256; ++b) {
        chunk_off[b * NRANGE + r] = run;
        run += counts[b * NRANGE + r];
    }
    lds[r] = run;
    __syncthreads();
    int s = run;
    #pragma unroll
    for (int d = 1; d < 256; d <<= 1) {
        int t = (r >= d) ? lds[r - d] : 0;
        __syncthreads();
        lds[r] += t;
        __syncthreads();
    }
    int base = lds[r] - s;
    range_base[r] = base;
    if (r == 255) range_base[256] = lds[255];
    for (int b = 0; b < 256; ++b) chunk_off[b * NRANGE + r] += base;
}

__device__ __forceinline__ void dev_kc(int bid, const int* __restrict__ inc_node,
                                       const int* __restrict__ inc_hedge,
                                       const int* __restrict__ chunk_off,
                                       int2* __restrict__ bucket, int* __restrict__ lds) {
    int tid = threadIdx.x;
    lds[tid] = 0;
    __syncthreads();
    int s = bid * EPB, e = s + EPB;
    const int* co = chunk_off + bid * NRANGE;
    for (int i = s + tid; i < e; i += 256) {
        int v = inc_node[i];
        int h = inc_hedge[i];
        int rg = (unsigned)v / NPR;
        int rank = atomicAdd(&lds[rg], 1);
        bucket[co[rg] + rank] = make_int2(v, h);
    }
}

// lds layout: hist[768] | tsum[256] | cur[768]  (1792 ints)
__device__ __forceinline__ void dev_kd(int r, const int2* __restrict__ bucket,
                                       const int* __restrict__ range_base,
                                       int* __restrict__ node_off, int* __restrict__ csr,
                                       int* __restrict__ lds) {
    int tid = threadIdx.x;
    int* hist = lds;
    int* tsum = lds + 768;
    int* cur  = lds + 1024;
    for (int i = tid; i < 768; i += 256) { hist[i] = 0; cur[i] = 0; }
    __syncthreads();
    int lo = r * NPR;
    int pb = range_base[r], pe = range_base[r + 1];
    for (int i = pb + tid; i < pe; i += 256)
        atomicAdd(&hist[bucket[i].x - lo], 1);
    __syncthreads();
    int b3 = tid * 3;
    int a0 = hist[b3], a1 = hist[b3 + 1], a2 = hist[b3 + 2];
    int s = a0 + a1 + a2;
    tsum[tid] = s;
    __syncthreads();
    #pragma unroll
    for (int d = 1; d < 256; d <<= 1) {
        int t = (tid >= d) ? tsum[tid - d] : 0;
        __syncthreads();
        tsum[tid] += t;
        __syncthreads();
    }
    int excl = tsum[tid] - s;
    hist[b3]     = excl;
    hist[b3 + 1] = excl + a0;
    hist[b3 + 2] = excl + a0 + a1;
    __syncthreads();
    for (int v = tid; v < NPR; v += 256) node_off[lo + v] = pb + hist[v];
    if (r == NRANGE - 1 && tid == 0) node_off[N_NODES] = N_INC;
    for (int i = pb + tid; i < pe; i += 256) {
        int2 p = bucket[i];
        int l = p.x - lo;
        int k = atomicAdd(&cur[l], 1);
        csr[pb + hist[l] + k] = p.y;
    }
}

// ---------------------------------------------------------------------------
// col-split barrier-free MFMA GEMM: wave = 16 rows x 16 cols (1 MFMA/k-step).
// wid>>2 = row group, wid&3 = col block; the 4 waves of a block share the same
// A rows (L1-served). Register prefetch of the next k-tile hides load latency.
// ---------------------------------------------------------------------------
template <int BF16_OUT, int GATHER, int KK>
__device__ __forceinline__ void dev_gemm_cs(int wid, const float* __restrict__ A,
                                            const int* __restrict__ tok,
                                            const u16* __restrict__ Bt,
                                            const float* __restrict__ bias,
                                            void* __restrict__ C, int M) {
    int lane = threadIdx.x & 63;
    int m16 = lane & 15, q = lane >> 4;
    int rg = wid >> 2, jb = wid & 3;
    int base = rg << 4;
    if (base >= M) return;
    int row = base + m16;
    const float* arow = GATHER ? (A + ((size_t)tok[row] << 6))
                               : (A + (size_t)row * KK);
    const u16* brow = Bt + (size_t)(jb * 16 + m16) * KK + q * 8;
    const float* ap = arow + q * 8;

    f32x4 acc = {0.f, 0.f, 0.f, 0.f};
    float4 a0 = *reinterpret_cast<const float4*>(ap);
    float4 a1 = *reinterpret_cast<const float4*>(ap + 4);

    #pragma unroll 4
    for (int kt = 0; kt < KK; kt += 32) {
        float4 n0, n1;
        if (kt + 32 < KK) {
            n0 = *reinterpret_cast<const float4*>(ap + kt + 32);
            n1 = *reinterpret_cast<const float4*>(ap + kt + 36);
        }
        short8 a;
        a[0] = (short)f2bf(a0.x); a[1] = (short)f2bf(a0.y);
        a[2] = (short)f2bf(a0.z); a[3] = (short)f2bf(a0.w);
        a[4] = (short)f2bf(a1.x); a[5] = (short)f2bf(a1.y);
        a[6] = (short)f2bf(a1.z); a[7] = (short)f2bf(a1.w);
        short8 b = *reinterpret_cast<const short8*>(brow + kt);
        acc = __builtin_amdgcn_mfma_f32_16x16x32_bf16(a, b, acc, 0, 0, 0);
        a0 = n0; a1 = n1;
    }

    #pragma unroll
    for (int r = 0; r < 4; ++r) {
        int gr = base + q * 4 + r;
        int col = jb * 16 + m16;
        float v = acc[r];
        if (!BF16_OUT) v += bias[col];
        if (BF16_OUT)
            ((u16*)C)[(size_t)gr * 64 + col] = f2bf(v);
        else
            ((float*)C)[(size_t)gr * 64 + col] = v;
    }
}

// ---------------------------------------------------------------------------
// hedge_sum: one 8-lane subgroup per hedge (8 hedges/wave)
// ---------------------------------------------------------------------------
__device__ __forceinline__ void dev_hedge_sum(int bid, const int* __restrict__ inc_node,
                                              const int* __restrict__ he_off,
                                              const u16* __restrict__ xt,
                                              u16* __restrict__ he) {
    int w = (bid * 256 + (int)threadIdx.x) >> 6;
    int lane = threadIdx.x & 63;
    int sub = lane >> 3;
    int c8 = (lane & 7) << 3;
    int hedge = w * 8 + sub;
    if (hedge >= N_HE) return;
    int s = he_off[hedge], e = he_off[hedge + 1];

    float a0 = 0.f, a1 = 0.f, a2 = 0.f, a3 = 0.f;
    float a4 = 0.f, a5 = 0.f, a6 = 0.f, a7 = 0.f;

    int idx = (s < e) ? inc_node[s] : 0;
    for (int j = s; j < e; ++j) {
        int cur = idx;
        if (j + 1 < e) idx = inc_node[j + 1];
        uint4 d = *reinterpret_cast<const uint4*>(xt + (((size_t)cur) << 6) + c8);
        a0 += lo_bf(d.x); a1 += hi_bf(d.x);
        a2 += lo_bf(d.y); a3 += hi_bf(d.y);
        a4 += lo_bf(d.z); a5 += hi_bf(d.z);
        a6 += lo_bf(d.w); a7 += hi_bf(d.w);
    }

    float inv = (e > s) ? 1.f / (float)(e - s) : 0.f;
    uint4 o;
    o.x = pack_bf2(a0 * inv, a1 * inv);
    o.y = pack_bf2(a2 * inv, a3 * inv);
    o.z = pack_bf2(a4 * inv, a5 * inv);
    o.w = pack_bf2(a6 * inv, a7 * inv);
    *reinterpret_cast<uint4*>(he + (((size_t)hedge) << 6) + c8) = o;
}

// node_sum with residual gathered from P[tok[node]]
__device__ __forceinline__ void dev_node_sum(int bid, const int* __restrict__ csr,
                                             const int* __restrict__ node_off,
                                             const u16* __restrict__ he,
                                             const float* __restrict__ bias,
                                             const float* __restrict__ P,
                                             const int* __restrict__ tok,
                                             float* __restrict__ out) {
    int w = (bid * 256 + (int)threadIdx.x) >> 6;
    int lane = threadIdx.x & 63;
    int sub = lane >> 3;
    int c8 = (lane & 7) << 3;
    int node = w * 8 + sub;
    if (node >= N_NODES) return;
    int s = node_off[node], e = node_off[node + 1];

    float a0 = 0.f, a1 = 0.f, a2 = 0.f, a3 = 0.f;
    float a4 = 0.f, a5 = 0.f, a6 = 0.f, a7 = 0.f;

    int idx = (s < e) ? csr[s] : 0;
    for (int j = s; j < e; ++j) {
        int cur = idx;
        if (j + 1 < e) idx = csr[j + 1];
        uint4 d = *reinterpret_cast<const uint4*>(he + (((size_t)cur) << 6) + c8);
        a0 += lo_bf(d.x); a1 += hi_bf(d.x);
        a2 += lo_bf(d.y); a3 += hi_bf(d.y);
        a4 += lo_bf(d.z); a5 += hi_bf(d.z);
        a6 += lo_bf(d.w); a7 += hi_bf(d.w);
    }

    float inv = (e > s) ? 1.f / (float)(e - s) : 0.f;
    const float* nfp = P + (((size_t)tok[node]) << 6) + c8;
    float4 nv0 = *reinterpret_cast<const float4*>(nfp);
    float4 nv1 = *reinterpret_cast<const float4*>(nfp + 4);
    float4 o0, o1;
    o0.x = fmaxf(fmaf(a0, inv, bias[c8 + 0]), 0.f) + nv0.x;
    o0.y = fmaxf(fmaf(a1, inv, bias[c8 + 1]), 0.f) + nv0.y;
    o0.z = fmaxf(fmaf(a2, inv, bias[c8 + 2]), 0.f) + nv0.z;
    o0.w = fmaxf(fmaf(a3, inv, bias[c8 + 3]), 0.f) + nv0.w;
    o1.x = fmaxf(fmaf(a4, inv, bias[c8 + 4]), 0.f) + nv1.x;
    o1.y = fmaxf(fmaf(a5, inv, bias[c8 + 5]), 0.f) + nv1.y;
    o1.z = fmaxf(fmaf(a6, inv, bias[c8 + 6]), 0.f) + nv1.z;
    o1.w = fmaxf(fmaf(a7, inv, bias[c8 + 7]), 0.f) + nv1.w;
    float* op = out + (((size_t)node) << 6) + c8;
    *reinterpret_cast<float4*>(op) = o0;
    *reinterpret_cast<float4*>(op + 4) = o1;
}

// ---------------------------------------------------------------------------
// phase mega-kernels
// ---------------------------------------------------------------------------
__global__ __launch_bounds__(256) void k_p1(const int* __restrict__ inc_hedge,
                                            const int* __restrict__ node2cell,
                                            const int* __restrict__ inc_node,
                                            int* __restrict__ he_off, int* __restrict__ cell_off,
                                            int* __restrict__ counts,
                                            const float* __restrict__ fhi_w, const float* __restrict__ fin_w,
                                            const float* __restrict__ th1, const float* __restrict__ th2,
                                            u16* __restrict__ Bt_fhi, u16* __restrict__ Bt_fin,
                                            u16* __restrict__ Bt_th1, u16* __restrict__ Bt_th2) {
    __shared__ int lds[256];
    int bid = blockIdx.x;
    if (bid < G_OFF_HE) { dev_offsets(bid, inc_hedge, N_INC, N_HE, he_off); return; }
    bid -= G_OFF_HE;
    if (bid < G_KA) { dev_ka(bid, inc_node, counts, lds); return; }
    bid -= G_KA;
    if (bid < G_OFF_CELL) { dev_offsets(bid, node2cell, N_NODES, N_CELLS, cell_off); return; }
    bid -= G_OFF_CELL;
    if (bid < G_CONV_BIG) { dev_convT(bid, fhi_w, Bt_fhi, D_IN); return; }
    bid -= G_CONV_BIG;
    if (bid < G_CONV_BIG) { dev_convT(bid, fin_w, Bt_fin, D_IN); return; }
    bid -= G_CONV_BIG;
    if (bid < G_CONV_SM) { dev_convT(bid, th1, Bt_th1, 64); return; }
    bid -= G_CONV_SM;
    dev_convT(bid, th2, Bt_th2, 64);
}

// P2: P-GEMM (col-split) + Kb + x0-GEMM
__global__ __launch_bounds__(256) void k_p2(const int* __restrict__ counts,
                                            int* __restrict__ chunk_off, int* __restrict__ range_base,
                                            const float* __restrict__ vac_emb,
                                            const u16* __restrict__ Bt_fhi,
                                            const float* __restrict__ fhi_b, float* __restrict__ P,
                                            const float* __restrict__ x, const u16* __restrict__ Bt_fin,
                                            const float* __restrict__ fin_b, float* __restrict__ x0) {
    __shared__ int lds[256];
    int bid = blockIdx.x;
    if (bid < G_PGEMM) {
        int wid = bid * 4 + ((int)threadIdx.x >> 6);
        dev_gemm_cs<0, 0, D_IN>(wid, vac_emb, nullptr, Bt_fhi, fhi_b, P, VOCAB);
        return;
    }
    bid -= G_PGEMM;
    if (bid < G_X0) {
        int wid = bid * 4 + ((int)threadIdx.x >> 6);
        dev_gemm_cs<0, 0, D_IN>(wid, x, nullptr, Bt_fin, fin_b, x0, I_ * J_);
        return;
    }
    dev_kb(counts, chunk_off, range_base, lds);
}

// P3: xt-GEMM L1 (gather-A, col-split) + Kc
__global__ __launch_bounds__(256) void k_p3(const float* __restrict__ P,
                                            const int* __restrict__ tok,
                                            const u16* __restrict__ Bt_th1, u16* __restrict__ xt,
                                            const int* __restrict__ inc_node,
                                            const int* __restrict__ inc_hedge,
                                            const int* __restrict__ chunk_off,
                                            int2* __restrict__ bucket) {
    __shared__ int lds[256];
    int bid = blockIdx.x;
    if (bid < G_XT) {
        int wid = bid * 4 + ((int)threadIdx.x >> 6);
        dev_gemm_cs<1, 1, 64>(wid, P, tok, Bt_th1, nullptr, xt, N_NODES);
        return;
    }
    bid -= G_XT;
    dev_kc(bid, inc_node, inc_hedge, chunk_off, bucket, lds);
}

// P4: hedge_sum L1 + Kd
__global__ __launch_bounds__(256) void k_p4(const int* __restrict__ inc_node,
                                            const int* __restrict__ he_off,
                                            const u16* __restrict__ xt, u16* __restrict__ he,
                                            const int2* __restrict__ bucket,
                                            const int* __restrict__ range_base,
                                            int* __restrict__ node_off, int* __restrict__ csr) {
    __shared__ int lds[1792];
    int bid = blockIdx.x;
    if (bid < G_HEDGE) { dev_hedge_sum(bid, inc_node, he_off, xt, he); return; }
    bid -= G_HEDGE;
    dev_kd(bid, bucket, range_base, node_off, csr, lds);
}

// standalone wrappers
__global__ __launch_bounds__(256) void k_xt2(const float* __restrict__ A,
                                             const u16* __restrict__ Bt,
                                             u16* __restrict__ xt) {
    int wid = blockIdx.x * 4 + ((int)threadIdx.x >> 6);
    dev_gemm_cs<1, 0, 64>(wid, A, nullptr, Bt, nullptr, xt, N_NODES);
}

__global__ __launch_bounds__(256) void k_hedge_sum(const int* __restrict__ inc_node,
                                                   const int* __restrict__ he_off,
                                                   const u16* __restrict__ xt,
                                                   u16* __restrict__ he) {
    dev_hedge_sum(blockIdx.x, inc_node, he_off, xt, he);
}

__global__ __launch_bounds__(256) void k_node_sum(const int* __restrict__ csr,
                                                  const int* __restrict__ node_off,
                                                  const u16* __restrict__ he,
                                                  const float* __restrict__ bias,
                                                  const float* __restrict__ P,
                                                  const int* __restrict__ tok,
                                                  float* __restrict__ out) {
    dev_node_sum(blockIdx.x, csr, node_off, he, bias, P, tok, out);
}

// ---------------------------------------------------------------------------
__global__ __launch_bounds__(256) void k_pool(const float* __restrict__ gx,
                                              const int* __restrict__ cell_off,
                                              const float* __restrict__ x0,
                                              float* __restrict__ out1) {
    __shared__ float ssum[4][64];
    __shared__ float smax[4][64];
    int c = blockIdx.x;
    int lane = threadIdx.x & 63;
    int w = threadIdx.x >> 6;
    int s = cell_off[c], e = cell_off[c + 1];
    float sum = 0.f, mx = -INFINITY;
    for (int n = s + w; n < e; n += 4) {
        float v = gx[((size_t)n << 6) + lane];
        sum += v;
        mx = fmaxf(mx, v);
    }
    ssum[w][lane] = sum;
    smax[w][lane] = mx;
    __syncthreads();
    if (w == 0) {
        sum = ssum[0][lane] + ssum[1][lane] + ssum[2][lane] + ssum[3][lane];
        mx = fmaxf(fmaxf(smax[0][lane], smax[1][lane]), fmaxf(smax[2][lane], smax[3][lane]));
        int cnt = e - s;
        float mean = (cnt > 0) ? sum / (float)cnt : 0.f;
        float mp = (cnt > 0) ? mx : 0.f;
        float ce = 0.5f * (mean + mp);
        out1[((size_t)c << 6) + lane] = x0[((size_t)c << 6) + lane] + 0.3f * ce;
    }
}

// ---------------------------------------------------------------------------
__global__ __launch_bounds__(256) void k_tcn(
    const float* __restrict__ xu,
    const float* __restrict__ wc1, const float* __restrict__ bc1, const float* __restrict__ g1,
    const float* __restrict__ be1, const float* __restrict__ m1, const float* __restrict__ v1,
    const float* __restrict__ wc2, const float* __restrict__ bc2, const float* __restrict__ g2,
    const float* __restrict__ be2, const float* __restrict__ m2, const float* __restrict__ v2,
    const float* __restrict__ wc3, const float* __restrict__ bc3, const float* __restrict__ g3,
    const float* __restrict__ be3, const float* __restrict__ m3, const float* __restrict__ v3,
    const float* __restrict__ fct_w, const float* __restrict__ fct_b,
    float* __restrict__ out2) {
    __shared__ float w_lds[64 * 64 * 3];
    __shared__ float hA[64][10];
    __shared__ float hB[64][10];
    __shared__ float mo[64];

    int n = blockIdx.x, tid = threadIdx.x;

    if (tid < 64) {
        hA[tid][0] = 0.f; hA[tid][9] = 0.f;
        hB[tid][0] = 0.f; hB[tid][9] = 0.f;
    }
    #pragma unroll
    for (int l = tid; l < 512; l += 256) {
        int t = l >> 6, i = l & 63;
        hA[i][t + 1] = xu[(size_t)n * 512 + l];
    }

    const float* wcs[3] = {wc1, wc2, wc3};
    const float* bcs[3] = {bc1, bc2, bc3};
    const float* gs[3]  = {g1, g2, g3};
    const float* bes[3] = {be1, be2, be3};
    const float* ms[3]  = {m1, m2, m3};
    const float* vs[3]  = {v1, v2, v3};

    float (*hin)[10] = hA;
    float (*hout)[10] = hB;

    #pragma unroll
    for (int li = 0; li < 3; ++li) {
        for (int l = tid; l < 64 * 64 * 3; l += 256) w_lds[l] = wcs[li][l];
        __syncthreads();
        #pragma unroll
        for (int rep = 0; rep < 2; ++rep) {
            int idx = tid + rep * 256;
            int o = idx >> 3, t = idx & 7;
            float acc = bcs[li][o];
            #pragma unroll 8
            for (int i = 0; i < 64; ++i) {
                const float* wr = &w_lds[o * 192 + i * 3];
                acc = fmaf(hin[i][t + 0], wr[0], acc);
                acc = fmaf(hin[i][t + 1], wr[1], acc);
                acc = fmaf(hin[i][t + 2], wr[2], acc);
            }
            acc = fmaxf(acc, 0.f);
            float sc = gs[li][o] * rsqrtf(vs[li][o] + 1e-5f);
            acc = (acc - ms[li][o]) * sc + bes[li][o];
            hout[o][t + 1] = acc;
        }
        __syncthreads();
        float (*tmp)[10] = hin; hin = hout; hout = tmp;
    }

    if (tid < 64) {
        float s = 0.f;
        #pragma unroll
        for (int t = 0; t < 8; ++t) s += hin[tid][t + 1];
        mo[tid] = s * 0.125f;
    }
    __syncthreads();
    if (tid < 64) {
        float acc = fct_b[tid];
        #pragma unroll 8
        for (int o = 0; o < 64; ++o) acc = fmaf(mo[o], fct_w[o * 64 + tid], acc);
        out2[(size_t)n * 64 + tid] = acc;
    }
}

// ---------------------------------------------------------------------------
extern "C" void kernel_launch(void* const* d_in, const int* in_sizes, int n_in,
                              void* d_out, int out_size, void* d_ws, size_t ws_size,
                              hipStream_t stream) {
    (void)in_sizes; (void)n_in; (void)out_size; (void)ws_size;

    const float* x          = (const float*)d_in[0];
    const int*   node_tok   = (const int*)d_in[1];
    const int*   inc_node   = (const int*)d_in[2];
    const int*   inc_hedge  = (const int*)d_in[3];
    const int*   node2cell  = (const int*)d_in[4];
    const float* vac_emb    = (const float*)d_in[5];
    const float* fhi_w      = (const float*)d_in[6];
    const float* fhi_b      = (const float*)d_in[7];
    const float* fin_w      = (const float*)d_in[8];
    const float* fin_b      = (const float*)d_in[9];
    const float* th1        = (const float*)d_in[10];
    const float* b1         = (const float*)d_in[11];
    const float* th2        = (const float*)d_in[12];
    const float* b2         = (const float*)d_in[13];
    const float* fct_w      = (const float*)d_in[32];
    const float* fct_b      = (const float*)d_in[33];

    char* ws = (char*)d_ws;
    size_t off = 0;
    float* P        = (float*)(ws + off); off += (size_t)VOCAB * 64 * 4;
    float* hbuf     = (float*)(ws + off); off += (size_t)N_NODES * 64 * 4;
    u16*   xt       = (u16*)(ws + off);   off += (size_t)N_NODES * 64 * 2;
    u16*   he       = (u16*)(ws + off);   off += (size_t)N_HE * 64 * 2;
    int2*  bucket   = (int2*)(ws + off);  off += (size_t)N_INC * 8;
    float* x0       = (float*)(ws + off); off += (size_t)N_CELLS * 64 * 4;
    u16*   Bt_fhi   = (u16*)(ws + off);   off += (size_t)64 * D_IN * 2;
    u16*   Bt_fin   = (u16*)(ws + off);   off += (size_t)64 * D_IN * 2;
    u16*   Bt_th1   = (u16*)(ws + off);   off += (size_t)64 * 64 * 2;
    u16*   Bt_th2   = (u16*)(ws + off);   off += (size_t)64 * 64 * 2;
    int*   he_off   = (int*)(ws + off);   off += ((size_t)(N_HE + 1) * 4 + 255) / 256 * 256;
    int*   node_off = (int*)(ws + off);   off += ((size_t)(N_NODES + 1) * 4 + 255) / 256 * 256;
    int*   csr      = (int*)(ws + off);   off += (size_t)N_INC * 4;
    int*   cell_off = (int*)(ws + off);   off += ((size_t)(N_CELLS + 1) * 4 + 255) / 256 * 256;

    // counts/chunk_off/range_base alias hbuf (dead before node_sum L1 writes hbuf)
    int*  counts     = (int*)hbuf;
    int*  chunk_off  = counts + 256 * 256;
    int*  range_base = chunk_off + 256 * 256;

    float* out1 = (float*)d_out;
    float* out2 = out1 + (size_t)I_ * J_ * D_H;

    // P1: offsets(hedge) + Ka + offsets(cell) + 4x convT
    k_p1<<<G_OFF_HE + G_KA + G_OFF_CELL + 2 * G_CONV_BIG + 2 * G_CONV_SM, 256, 0, stream>>>(
        inc_hedge, node2cell, inc_node, he_off, cell_off, counts,
        fhi_w, fin_w, th1, th2, Bt_fhi, Bt_fin, Bt_th1, Bt_th2);

    // P2: P-GEMM (col-split) + x0-GEMM + Kb
    k_p2<<<G_PGEMM + G_X0 + 1, 256, 0, stream>>>(counts, chunk_off, range_base,
                                                 vac_emb, Bt_fhi, fhi_b, P,
                                                 x, Bt_fin, fin_b, x0);

    // P3: xt-GEMM L1 (gather-A, col-split) + Kc
    k_p3<<<G_XT + G_KC, 256, 0, stream>>>(P, node_tok, Bt_th1, xt,
                                          inc_node, inc_hedge, chunk_off, bucket);

    // P4: hedge_sum L1 + Kd
    k_p4<<<G_HEDGE + G_KD, 256, 0, stream>>>(inc_node, he_off, xt, he,
                                             bucket, range_base, node_off, csr);

    // P5: node_sum L1 -> hbuf = h1
    k_node_sum<<<G_NODE, 256, 0, stream>>>(csr, node_off, he, b1, P, node_tok, hbuf);

    // P6: xt-GEMM L2 (dense A = hbuf)
    k_xt2<<<G_XT, 256, 0, stream>>>(hbuf, Bt_th2, xt);

    // P7: hedge_sum L2
    k_hedge_sum<<<G_HEDGE, 256, 0, stream>>>(inc_node, he_off, xt, he);

    // P8: node_sum L2 -> hbuf = gx
    k_node_sum<<<G_NODE, 256, 0, stream>>>(csr, node_off, he, b2, P, node_tok, hbuf);

    // P9: pool + fuse -> out1
    k_pool<<<N_CELLS, 256, 0, stream>>>(hbuf, cell_off, x0, out1);

    // P10: TCN -> out2
    k_tcn<<<I_, 256, 0, stream>>>(out1,
        (const float*)d_in[14], (const float*)d_in[15], (const float*)d_in[16],
        (const float*)d_in[17], (const float*)d_in[18], (const float*)d_in[19],
        (const float*)d_in[20], (const float*)d_in[21], (const float*)d_in[22],
        (const float*)d_in[23], (const float*)d_in[24], (const float*)d_in[25],
        (const float*)d_in[26], (const float*)d_in[27], (const float*)d_in[28],
        (const float*)d_in[29], (const float*)d_in[30], (const float*)d_in[31],
        fct_w, fct_b, out2);
}

// Round 10
// 581.140 us; speedup vs baseline: 1.0616x; 1.0616x over previous
//
#include <hip/hip_runtime.h>
#include <hip/hip_bf16.h>
#include <cstdint>
#include <cstddef>

#define I_      100
#define J_      8
#define D_IN    768
#define D_H     64
#define N_NODES 160000
#define N_HE    320000
#define N_INC   1600000
#define N_CELLS 800
#define VOCAB   30000

#define NRANGE   256
#define NPR      625
#define EPB      (N_INC / 256)

typedef unsigned short u16;
using short8 = __attribute__((ext_vector_type(8))) short;
using f32x4  = __attribute__((ext_vector_type(4))) float;

__device__ __forceinline__ float bf2f(u16 u) {
    union { uint32_t i; float f; } x; x.i = ((uint32_t)u) << 16; return x.f;
}
__device__ __forceinline__ u16 f2bf(float f) {
    union { float f; uint32_t i; } x; x.f = f;
    uint32_t b = x.i;
    b += 0x7FFFu + ((b >> 16) & 1u);
    return (u16)(b >> 16);
}
__device__ __forceinline__ float lo_bf(uint32_t u) {
    union { uint32_t i; float f; } x; x.i = u << 16; return x.f;
}
__device__ __forceinline__ float hi_bf(uint32_t u) {
    union { uint32_t i; float f; } x; x.i = u & 0xFFFF0000u; return x.f;
}
__device__ __forceinline__ uint32_t pack_bf2(float a, float b) {
    return (uint32_t)f2bf(a) | ((uint32_t)f2bf(b) << 16);
}

// grid-partition constants
#define G_OFF_HE   (N_INC / 256)        // 6250
#define G_OFF_CELL (N_NODES / 256)      // 625
#define G_CONV_BIG ((D_IN * 64) / 256)  // 192
#define G_CONV_SM  ((64 * 64) / 256)    // 16
#define G_KA       256
#define G_KC       256
#define G_KD       256
#define G_PGEMM    ((VOCAB + 63) / 64)  // 469  (R8 row-split: 16 rows/wave, 64 cols)
#define G_XT       (N_NODES / 64)       // 2500
#define G_X0       ((I_ * J_ + 63) / 64)// 13
#define G_HEDGE    (N_HE / 32)          // 10000 (8 hedges/wave)
#define G_NODE     (N_NODES / 32)       // 5000

// ---------------------------------------------------------------------------
__device__ __forceinline__ void dev_offsets(int bid, const int* __restrict__ sorted,
                                            int n, int nbins, int* __restrict__ off) {
    int i = bid * 256 + threadIdx.x;
    if (i >= n) return;
    int cur = sorted[i];
    int prev = (i == 0) ? -1 : sorted[i - 1];
    for (int b = prev + 1; b <= cur; ++b) off[b] = i;
    if (i == n - 1) {
        for (int b = cur + 1; b <= nbins; ++b) off[b] = n;
    }
}

__device__ __forceinline__ void dev_convT(int bid, const float* __restrict__ B,
                                          u16* __restrict__ Bt, int K) {
    int g = bid * 256 + threadIdx.x;
    if (g >= K * 64) return;
    int k = g >> 6, n = g & 63;
    Bt[(size_t)n * K + k] = f2bf(B[g]);
}

// ---------------------------------------------------------------------------
// bucket-sort CSR build
// ---------------------------------------------------------------------------
__device__ __forceinline__ void dev_ka(int bid, const int* __restrict__ inc_node,
                                       int* __restrict__ counts, int* __restrict__ lds) {
    int tid = threadIdx.x;
    lds[tid] = 0;
    __syncthreads();
    int s = bid * EPB, e = s + EPB;
    for (int i = s + tid; i < e; i += 256)
        atomicAdd(&lds[(unsigned)inc_node[i] / NPR], 1);
    __syncthreads();
    counts[bid * NRANGE + tid] = lds[tid];
}

__device__ __forceinline__ void dev_kb(const int* __restrict__ counts,
                                       int* __restrict__ chunk_off,
                                       int* __restrict__ range_base,
                                       int* __restrict__ lds) {
    int r = threadIdx.x;
    int run = 0;
    for (int b = 0; b < 256; ++b) {
        chunk_off[b * NRANGE + r] = run;
        run += counts[b * NRANGE + r];
    }
    lds[r] = run;
    __syncthreads();
    int s = run;
    #pragma unroll
    for (int d = 1; d < 256; d <<= 1) {
        int t = (r >= d) ? lds[r - d] : 0;
        __syncthreads();
        lds[r] += t;
        __syncthreads();
    }
    int base = lds[r] - s;
    range_base[r] = base;
    if (r == 255) range_base[256] = lds[255];
    for (int b = 0; b < 256; ++b) chunk_off[b * NRANGE + r] += base;
}

__device__ __forceinline__ void dev_kc(int bid, const int* __restrict__ inc_node,
                                       const int* __restrict__ inc_hedge,
                                       const int* __restrict__ chunk_off,
                                       int2* __restrict__ bucket, int* __restrict__ lds) {
    int tid = threadIdx.x;
    lds[tid] = 0;
    __syncthreads();
    int s = bid * EPB, e = s + EPB;
    const int* co = chunk_off + bid * NRANGE;
    for (int i = s + tid; i < e; i += 256) {
        int v = inc_node[i];
        int h = inc_hedge[i];
        int rg = (unsigned)v / NPR;
        int rank = atomicAdd(&lds[rg], 1);
        bucket[co[rg] + rank] = make_int2(v, h);
    }
}

// lds layout: hist[768] | tsum[256] | cur[768]  (1792 ints)
__device__ __forceinline__ void dev_kd(int r, const int2* __restrict__ bucket,
                                       const int* __restrict__ range_base,
                                       int* __restrict__ node_off, int* __restrict__ csr,
                                       int* __restrict__ lds) {
    int tid = threadIdx.x;
    int* hist = lds;
    int* tsum = lds + 768;
    int* cur  = lds + 1024;
    for (int i = tid; i < 768; i += 256) { hist[i] = 0; cur[i] = 0; }
    __syncthreads();
    int lo = r * NPR;
    int pb = range_base[r], pe = range_base[r + 1];
    for (int i = pb + tid; i < pe; i += 256)
        atomicAdd(&hist[bucket[i].x - lo], 1);
    __syncthreads();
    int b3 = tid * 3;
    int a0 = hist[b3], a1 = hist[b3 + 1], a2 = hist[b3 + 2];
    int s = a0 + a1 + a2;
    tsum[tid] = s;
    __syncthreads();
    #pragma unroll
    for (int d = 1; d < 256; d <<= 1) {
        int t = (tid >= d) ? tsum[tid - d] : 0;
        __syncthreads();
        tsum[tid] += t;
        __syncthreads();
    }
    int excl = tsum[tid] - s;
    hist[b3]     = excl;
    hist[b3 + 1] = excl + a0;
    hist[b3 + 2] = excl + a0 + a1;
    __syncthreads();
    for (int v = tid; v < NPR; v += 256) node_off[lo + v] = pb + hist[v];
    if (r == NRANGE - 1 && tid == 0) node_off[N_NODES] = N_INC;
    for (int i = pb + tid; i < pe; i += 256) {
        int2 p = bucket[i];
        int l = p.x - lo;
        int k = atomicAdd(&cur[l], 1);
        csr[pb + hist[l] + k] = p.y;
    }
}

// ---------------------------------------------------------------------------
// R8 row-split barrier-free MFMA GEMM: one wave owns 16 rows x 64 cols
// (4 MFMA/k-step); A loaded straight from global, B from L2-resident Bt.
// ---------------------------------------------------------------------------
template <int BF16_OUT, int GATHER, int KK>
__device__ __forceinline__ void dev_gemm_direct(int wid, const float* __restrict__ A,
                                                const int* __restrict__ tok,
                                                const u16* __restrict__ Bt,
                                                const float* __restrict__ bias,
                                                void* __restrict__ C, int M) {
    int lane = threadIdx.x & 63;
    int m16 = lane & 15, q = lane >> 4;
    int base = wid << 4;
    if (base >= M) return;
    int row = base + m16;
    const float* arow = GATHER ? (A + ((size_t)tok[row] << 6))
                               : (A + (size_t)row * KK);

    f32x4 acc0 = {0.f, 0.f, 0.f, 0.f};
    f32x4 acc1 = {0.f, 0.f, 0.f, 0.f};
    f32x4 acc2 = {0.f, 0.f, 0.f, 0.f};
    f32x4 acc3 = {0.f, 0.f, 0.f, 0.f};

    #pragma unroll 2
    for (int kt = 0; kt < KK; kt += 32) {
        const float* ap = arow + kt + q * 8;
        float4 av0 = *reinterpret_cast<const float4*>(ap);
        float4 av1 = *reinterpret_cast<const float4*>(ap + 4);
        short8 a;
        a[0] = (short)f2bf(av0.x); a[1] = (short)f2bf(av0.y);
        a[2] = (short)f2bf(av0.z); a[3] = (short)f2bf(av0.w);
        a[4] = (short)f2bf(av1.x); a[5] = (short)f2bf(av1.y);
        a[6] = (short)f2bf(av1.z); a[7] = (short)f2bf(av1.w);
        const u16* bp = Bt + (size_t)m16 * KK + kt + q * 8;
        short8 b0 = *reinterpret_cast<const short8*>(bp);
        short8 b1 = *reinterpret_cast<const short8*>(bp + (size_t)16 * KK);
        short8 b2 = *reinterpret_cast<const short8*>(bp + (size_t)32 * KK);
        short8 b3 = *reinterpret_cast<const short8*>(bp + (size_t)48 * KK);
        acc0 = __builtin_amdgcn_mfma_f32_16x16x32_bf16(a, b0, acc0, 0, 0, 0);
        acc1 = __builtin_amdgcn_mfma_f32_16x16x32_bf16(a, b1, acc1, 0, 0, 0);
        acc2 = __builtin_amdgcn_mfma_f32_16x16x32_bf16(a, b2, acc2, 0, 0, 0);
        acc3 = __builtin_amdgcn_mfma_f32_16x16x32_bf16(a, b3, acc3, 0, 0, 0);
    }

    f32x4 accs[4] = {acc0, acc1, acc2, acc3};
    #pragma unroll
    for (int r = 0; r < 4; ++r) {
        int gr = base + q * 4 + r;
        #pragma unroll
        for (int j = 0; j < 4; ++j) {
            int col = j * 16 + m16;
            float v = accs[j][r];
            if (!BF16_OUT) v += bias[col];
            if (BF16_OUT)
                ((u16*)C)[(size_t)gr * 64 + col] = f2bf(v);
            else
                ((float*)C)[(size_t)gr * 64 + col] = v;
        }
    }
}

// ---------------------------------------------------------------------------
// hedge_sum: one 8-lane subgroup per hedge (8 hedges/wave)
// ---------------------------------------------------------------------------
__device__ __forceinline__ void dev_hedge_sum(int bid, const int* __restrict__ inc_node,
                                              const int* __restrict__ he_off,
                                              const u16* __restrict__ xt,
                                              u16* __restrict__ he) {
    int w = (bid * 256 + (int)threadIdx.x) >> 6;
    int lane = threadIdx.x & 63;
    int sub = lane >> 3;
    int c8 = (lane & 7) << 3;
    int hedge = w * 8 + sub;
    if (hedge >= N_HE) return;
    int s = he_off[hedge], e = he_off[hedge + 1];

    float a0 = 0.f, a1 = 0.f, a2 = 0.f, a3 = 0.f;
    float a4 = 0.f, a5 = 0.f, a6 = 0.f, a7 = 0.f;

    int idx = (s < e) ? inc_node[s] : 0;
    for (int j = s; j < e; ++j) {
        int cur = idx;
        if (j + 1 < e) idx = inc_node[j + 1];
        uint4 d = *reinterpret_cast<const uint4*>(xt + (((size_t)cur) << 6) + c8);
        a0 += lo_bf(d.x); a1 += hi_bf(d.x);
        a2 += lo_bf(d.y); a3 += hi_bf(d.y);
        a4 += lo_bf(d.z); a5 += hi_bf(d.z);
        a6 += lo_bf(d.w); a7 += hi_bf(d.w);
    }

    float inv = (e > s) ? 1.f / (float)(e - s) : 0.f;
    uint4 o;
    o.x = pack_bf2(a0 * inv, a1 * inv);
    o.y = pack_bf2(a2 * inv, a3 * inv);
    o.z = pack_bf2(a4 * inv, a5 * inv);
    o.w = pack_bf2(a6 * inv, a7 * inv);
    *reinterpret_cast<uint4*>(he + (((size_t)hedge) << 6) + c8) = o;
}

// node_sum with residual gathered from P[tok[node]]
__device__ __forceinline__ void dev_node_sum(int bid, const int* __restrict__ csr,
                                             const int* __restrict__ node_off,
                                             const u16* __restrict__ he,
                                             const float* __restrict__ bias,
                                             const float* __restrict__ P,
                                             const int* __restrict__ tok,
                                             float* __restrict__ out) {
    int w = (bid * 256 + (int)threadIdx.x) >> 6;
    int lane = threadIdx.x & 63;
    int sub = lane >> 3;
    int c8 = (lane & 7) << 3;
    int node = w * 8 + sub;
    if (node >= N_NODES) return;
    int s = node_off[node], e = node_off[node + 1];

    float a0 = 0.f, a1 = 0.f, a2 = 0.f, a3 = 0.f;
    float a4 = 0.f, a5 = 0.f, a6 = 0.f, a7 = 0.f;

    int idx = (s < e) ? csr[s] : 0;
    for (int j = s; j < e; ++j) {
        int cur = idx;
        if (j + 1 < e) idx = csr[j + 1];
        uint4 d = *reinterpret_cast<const uint4*>(he + (((size_t)cur) << 6) + c8);
        a0 += lo_bf(d.x); a1 += hi_bf(d.x);
        a2 += lo_bf(d.y); a3 += hi_bf(d.y);
        a4 += lo_bf(d.z); a5 += hi_bf(d.z);
        a6 += lo_bf(d.w); a7 += hi_bf(d.w);
    }

    float inv = (e > s) ? 1.f / (float)(e - s) : 0.f;
    const float* nfp = P + (((size_t)tok[node]) << 6) + c8;
    float4 nv0 = *reinterpret_cast<const float4*>(nfp);
    float4 nv1 = *reinterpret_cast<const float4*>(nfp + 4);
    float4 o0, o1;
    o0.x = fmaxf(fmaf(a0, inv, bias[c8 + 0]), 0.f) + nv0.x;
    o0.y = fmaxf(fmaf(a1, inv, bias[c8 + 1]), 0.f) + nv0.y;
    o0.z = fmaxf(fmaf(a2, inv, bias[c8 + 2]), 0.f) + nv0.z;
    o0.w = fmaxf(fmaf(a3, inv, bias[c8 + 3]), 0.f) + nv0.w;
    o1.x = fmaxf(fmaf(a4, inv, bias[c8 + 4]), 0.f) + nv1.x;
    o1.y = fmaxf(fmaf(a5, inv, bias[c8 + 5]), 0.f) + nv1.y;
    o1.z = fmaxf(fmaf(a6, inv, bias[c8 + 6]), 0.f) + nv1.z;
    o1.w = fmaxf(fmaf(a7, inv, bias[c8 + 7]), 0.f) + nv1.w;
    float* op = out + (((size_t)node) << 6) + c8;
    *reinterpret_cast<float4*>(op) = o0;
    *reinterpret_cast<float4*>(op + 4) = o1;
}

// ---------------------------------------------------------------------------
// phase mega-kernels
// ---------------------------------------------------------------------------
// P0: convT x4 + Ka
__global__ __launch_bounds__(256) void k_p0(const float* __restrict__ fhi_w,
                                            const float* __restrict__ fin_w,
                                            const float* __restrict__ th1,
                                            const float* __restrict__ th2,
                                            u16* __restrict__ Bt_fhi, u16* __restrict__ Bt_fin,
                                            u16* __restrict__ Bt_th1, u16* __restrict__ Bt_th2,
                                            const int* __restrict__ inc_node,
                                            int* __restrict__ counts) {
    __shared__ int lds[256];
    int bid = blockIdx.x;
    if (bid < G_KA) { dev_ka(bid, inc_node, counts, lds); return; }
    bid -= G_KA;
    if (bid < G_CONV_BIG) { dev_convT(bid, fhi_w, Bt_fhi, D_IN); return; }
    bid -= G_CONV_BIG;
    if (bid < G_CONV_BIG) { dev_convT(bid, fin_w, Bt_fin, D_IN); return; }
    bid -= G_CONV_BIG;
    if (bid < G_CONV_SM) { dev_convT(bid, th1, Bt_th1, 64); return; }
    bid -= G_CONV_SM;
    dev_convT(bid, th2, Bt_th2, 64);
}

// P1: P-GEMM (first, long-running) + offsets(hedge) + offsets(cell) + Kb
__global__ __launch_bounds__(256) void k_p1(const float* __restrict__ vac_emb,
                                            const u16* __restrict__ Bt_fhi,
                                            const float* __restrict__ fhi_b, float* __restrict__ P,
                                            const int* __restrict__ inc_hedge,
                                            const int* __restrict__ node2cell,
                                            int* __restrict__ he_off, int* __restrict__ cell_off,
                                            const int* __restrict__ counts,
                                            int* __restrict__ chunk_off, int* __restrict__ range_base) {
    __shared__ int lds[256];
    int bid = blockIdx.x;
    if (bid < G_PGEMM) {
        int wid = bid * 4 + ((int)threadIdx.x >> 6);
        dev_gemm_direct<0, 0, D_IN>(wid, vac_emb, nullptr, Bt_fhi, fhi_b, P, VOCAB);
        return;
    }
    bid -= G_PGEMM;
    if (bid < G_OFF_HE) { dev_offsets(bid, inc_hedge, N_INC, N_HE, he_off); return; }
    bid -= G_OFF_HE;
    if (bid < G_OFF_CELL) { dev_offsets(bid, node2cell, N_NODES, N_CELLS, cell_off); return; }
    bid -= G_OFF_CELL;
    dev_kb(counts, chunk_off, range_base, lds);
}

// P2: xt-GEMM L1 (gather-A) + x0-GEMM + Kc
__global__ __launch_bounds__(256) void k_p2(const float* __restrict__ P,
                                            const int* __restrict__ tok,
                                            const u16* __restrict__ Bt_th1, u16* __restrict__ xt,
                                            const float* __restrict__ x, const u16* __restrict__ Bt_fin,
                                            const float* __restrict__ fin_b, float* __restrict__ x0,
                                            const int* __restrict__ inc_node,
                                            const int* __restrict__ inc_hedge,
                                            const int* __restrict__ chunk_off,
                                            int2* __restrict__ bucket) {
    __shared__ int lds[256];
    int bid = blockIdx.x;
    if (bid < G_XT) {
        int wid = bid * 4 + ((int)threadIdx.x >> 6);
        dev_gemm_direct<1, 1, 64>(wid, P, tok, Bt_th1, nullptr, xt, N_NODES);
        return;
    }
    bid -= G_XT;
    if (bid < G_KC) { dev_kc(bid, inc_node, inc_hedge, chunk_off, bucket, lds); return; }
    bid -= G_KC;
    {
        int wid = bid * 4 + ((int)threadIdx.x >> 6);
        dev_gemm_direct<0, 0, D_IN>(wid, x, nullptr, Bt_fin, fin_b, x0, I_ * J_);
    }
}

// P3: hedge_sum L1 + Kd
__global__ __launch_bounds__(256) void k_p3(const int* __restrict__ inc_node,
                                            const int* __restrict__ he_off,
                                            const u16* __restrict__ xt, u16* __restrict__ he,
                                            const int2* __restrict__ bucket,
                                            const int* __restrict__ range_base,
                                            int* __restrict__ node_off, int* __restrict__ csr) {
    __shared__ int lds[1792];
    int bid = blockIdx.x;
    if (bid < G_HEDGE) { dev_hedge_sum(bid, inc_node, he_off, xt, he); return; }
    bid -= G_HEDGE;
    dev_kd(bid, bucket, range_base, node_off, csr, lds);
}

// standalone wrappers
__global__ __launch_bounds__(256) void k_xt2(const float* __restrict__ A,
                                             const u16* __restrict__ Bt,
                                             u16* __restrict__ xt) {
    int wid = blockIdx.x * 4 + ((int)threadIdx.x >> 6);
    dev_gemm_direct<1, 0, 64>(wid, A, nullptr, Bt, nullptr, xt, N_NODES);
}

__global__ __launch_bounds__(256) void k_hedge_sum(const int* __restrict__ inc_node,
                                                   const int* __restrict__ he_off,
                                                   const u16* __restrict__ xt,
                                                   u16* __restrict__ he) {
    dev_hedge_sum(blockIdx.x, inc_node, he_off, xt, he);
}

__global__ __launch_bounds__(256) void k_node_sum(const int* __restrict__ csr,
                                                  const int* __restrict__ node_off,
                                                  const u16* __restrict__ he,
                                                  const float* __restrict__ bias,
                                                  const float* __restrict__ P,
                                                  const int* __restrict__ tok,
                                                  float* __restrict__ out) {
    dev_node_sum(blockIdx.x, csr, node_off, he, bias, P, tok, out);
}

// ---------------------------------------------------------------------------
__global__ __launch_bounds__(256) void k_pool(const float* __restrict__ gx,
                                              const int* __restrict__ cell_off,
                                              const float* __restrict__ x0,
                                              float* __restrict__ out1) {
    __shared__ float ssum[4][64];
    __shared__ float smax[4][64];
    int c = blockIdx.x;
    int lane = threadIdx.x & 63;
    int w = threadIdx.x >> 6;
    int s = cell_off[c], e = cell_off[c + 1];
    float sum = 0.f, mx = -INFINITY;
    for (int n = s + w; n < e; n += 4) {
        float v = gx[((size_t)n << 6) + lane];
        sum += v;
        mx = fmaxf(mx, v);
    }
    ssum[w][lane] = sum;
    smax[w][lane] = mx;
    __syncthreads();
    if (w == 0) {
        sum = ssum[0][lane] + ssum[1][lane] + ssum[2][lane] + ssum[3][lane];
        mx = fmaxf(fmaxf(smax[0][lane], smax[1][lane]), fmaxf(smax[2][lane], smax[3][lane]));
        int cnt = e - s;
        float mean = (cnt > 0) ? sum / (float)cnt : 0.f;
        float mp = (cnt > 0) ? mx : 0.f;
        float ce = 0.5f * (mean + mp);
        out1[((size_t)c << 6) + lane] = x0[((size_t)c << 6) + lane] + 0.3f * ce;
    }
}

// ---------------------------------------------------------------------------
__global__ __launch_bounds__(256) void k_tcn(
    const float* __restrict__ xu,
    const float* __restrict__ wc1, const float* __restrict__ bc1, const float* __restrict__ g1,
    const float* __restrict__ be1, const float* __restrict__ m1, const float* __restrict__ v1,
    const float* __restrict__ wc2, const float* __restrict__ bc2, const float* __restrict__ g2,
    const float* __restrict__ be2, const float* __restrict__ m2, const float* __restrict__ v2,
    const float* __restrict__ wc3, const float* __restrict__ bc3, const float* __restrict__ g3,
    const float* __restrict__ be3, const float* __restrict__ m3, const float* __restrict__ v3,
    const float* __restrict__ fct_w, const float* __restrict__ fct_b,
    float* __restrict__ out2) {
    __shared__ float w_lds[64 * 64 * 3];
    __shared__ float hA[64][10];
    __shared__ float hB[64][10];
    __shared__ float mo[64];

    int n = blockIdx.x, tid = threadIdx.x;

    if (tid < 64) {
        hA[tid][0] = 0.f; hA[tid][9] = 0.f;
        hB[tid][0] = 0.f; hB[tid][9] = 0.f;
    }
    #pragma unroll
    for (int l = tid; l < 512; l += 256) {
        int t = l >> 6, i = l & 63;
        hA[i][t + 1] = xu[(size_t)n * 512 + l];
    }

    const float* wcs[3] = {wc1, wc2, wc3};
    const float* bcs[3] = {bc1, bc2, bc3};
    const float* gs[3]  = {g1, g2, g3};
    const float* bes[3] = {be1, be2, be3};
    const float* ms[3]  = {m1, m2, m3};
    const float* vs[3]  = {v1, v2, v3};

    float (*hin)[10] = hA;
    float (*hout)[10] = hB;

    #pragma unroll
    for (int li = 0; li < 3; ++li) {
        for (int l = tid; l < 64 * 64 * 3; l += 256) w_lds[l] = wcs[li][l];
        __syncthreads();
        #pragma unroll
        for (int rep = 0; rep < 2; ++rep) {
            int idx = tid + rep * 256;
            int o = idx >> 3, t = idx & 7;
            float acc = bcs[li][o];
            #pragma unroll 8
            for (int i = 0; i < 64; ++i) {
                const float* wr = &w_lds[o * 192 + i * 3];
                acc = fmaf(hin[i][t + 0], wr[0], acc);
                acc = fmaf(hin[i][t + 1], wr[1], acc);
                acc = fmaf(hin[i][t + 2], wr[2], acc);
            }
            acc = fmaxf(acc, 0.f);
            float sc = gs[li][o] * rsqrtf(vs[li][o] + 1e-5f);
            acc = (acc - ms[li][o]) * sc + bes[li][o];
            hout[o][t + 1] = acc;
        }
        __syncthreads();
        float (*tmp)[10] = hin; hin = hout; hout = tmp;
    }

    if (tid < 64) {
        float s = 0.f;
        #pragma unroll
        for (int t = 0; t < 8; ++t) s += hin[tid][t + 1];
        mo[tid] = s * 0.125f;
    }
    __syncthreads();
    if (tid < 64) {
        float acc = fct_b[tid];
        #pragma unroll 8
        for (int o = 0; o < 64; ++o) acc = fmaf(mo[o], fct_w[o * 64 + tid], acc);
        out2[(size_t)n * 64 + tid] = acc;
    }
}

// ---------------------------------------------------------------------------
extern "C" void kernel_launch(void* const* d_in, const int* in_sizes, int n_in,
                              void* d_out, int out_size, void* d_ws, size_t ws_size,
                              hipStream_t stream) {
    (void)in_sizes; (void)n_in; (void)out_size; (void)ws_size;

    const float* x          = (const float*)d_in[0];
    const int*   node_tok   = (const int*)d_in[1];
    const int*   inc_node   = (const int*)d_in[2];
    const int*   inc_hedge  = (const int*)d_in[3];
    const int*   node2cell  = (const int*)d_in[4];
    const float* vac_emb    = (const float*)d_in[5];
    const float* fhi_w      = (const float*)d_in[6];
    const float* fhi_b      = (const float*)d_in[7];
    const float* fin_w      = (const float*)d_in[8];
    const float* fin_b      = (const float*)d_in[9];
    const float* th1        = (const float*)d_in[10];
    const float* b1         = (const float*)d_in[11];
    const float* th2        = (const float*)d_in[12];
    const float* b2         = (const float*)d_in[13];
    const float* fct_w      = (const float*)d_in[32];
    const float* fct_b      = (const float*)d_in[33];

    char* ws = (char*)d_ws;
    size_t off = 0;
    float* P        = (float*)(ws + off); off += (size_t)VOCAB * 64 * 4;
    float* hbuf     = (float*)(ws + off); off += (size_t)N_NODES * 64 * 4;
    u16*   xt       = (u16*)(ws + off);   off += (size_t)N_NODES * 64 * 2;
    u16*   he       = (u16*)(ws + off);   off += (size_t)N_HE * 64 * 2;
    int2*  bucket   = (int2*)(ws + off);  off += (size_t)N_INC * 8;
    float* x0       = (float*)(ws + off); off += (size_t)N_CELLS * 64 * 4;
    u16*   Bt_fhi   = (u16*)(ws + off);   off += (size_t)64 * D_IN * 2;
    u16*   Bt_fin   = (u16*)(ws + off);   off += (size_t)64 * D_IN * 2;
    u16*   Bt_th1   = (u16*)(ws + off);   off += (size_t)64 * 64 * 2;
    u16*   Bt_th2   = (u16*)(ws + off);   off += (size_t)64 * 64 * 2;
    int*   he_off   = (int*)(ws + off);   off += ((size_t)(N_HE + 1) * 4 + 255) / 256 * 256;
    int*   node_off = (int*)(ws + off);   off += ((size_t)(N_NODES + 1) * 4 + 255) / 256 * 256;
    int*   csr      = (int*)(ws + off);   off += (size_t)N_INC * 4;
    int*   cell_off = (int*)(ws + off);   off += ((size_t)(N_CELLS + 1) * 4 + 255) / 256 * 256;

    // counts/chunk_off/range_base alias hbuf (dead before node_sum L1 writes hbuf;
    // last read: Kd in P3 reads range_base, node_sum L1 runs in the next phase)
    int*  counts     = (int*)hbuf;
    int*  chunk_off  = counts + 256 * 256;
    int*  range_base = chunk_off + 256 * 256;

    float* out1 = (float*)d_out;
    float* out2 = out1 + (size_t)I_ * J_ * D_H;

    // P0: convT x4 + Ka
    k_p0<<<G_KA + 2 * G_CONV_BIG + 2 * G_CONV_SM, 256, 0, stream>>>(
        fhi_w, fin_w, th1, th2, Bt_fhi, Bt_fin, Bt_th1, Bt_th2, inc_node, counts);

    // P1: P-GEMM + offsets(hedge) + offsets(cell) + Kb
    k_p1<<<G_PGEMM + G_OFF_HE + G_OFF_CELL + 1, 256, 0, stream>>>(
        vac_emb, Bt_fhi, fhi_b, P, inc_hedge, node2cell, he_off, cell_off,
        counts, chunk_off, range_base);

    // P2: xt-GEMM L1 (gather-A) + Kc + x0-GEMM
    k_p2<<<G_XT + G_KC + G_X0, 256, 0, stream>>>(P, node_tok, Bt_th1, xt,
                                                 x, Bt_fin, fin_b, x0,
                                                 inc_node, inc_hedge, chunk_off, bucket);

    // P3: hedge_sum L1 + Kd
    k_p3<<<G_HEDGE + G_KD, 256, 0, stream>>>(inc_node, he_off, xt, he,
                                             bucket, range_base, node_off, csr);

    // P4: node_sum L1 -> hbuf = h1
    k_node_sum<<<G_NODE, 256, 0, stream>>>(csr, node_off, he, b1, P, node_tok, hbuf);

    // P5: xt-GEMM L2 (dense A = hbuf)
    k_xt2<<<G_XT, 256, 0, stream>>>(hbuf, Bt_th2, xt);

    // P6: hedge_sum L2
    k_hedge_sum<<<G_HEDGE, 256, 0, stream>>>(inc_node, he_off, xt, he);

    // P7: node_sum L2 -> hbuf = gx
    k_node_sum<<<G_NODE, 256, 0, stream>>>(csr, node_off, he, b2, P, node_tok, hbuf);

    // P8: pool + fuse -> out1
    k_pool<<<N_CELLS, 256, 0, stream>>>(hbuf, cell_off, x0, out1);

    // P9: TCN -> out2
    k_tcn<<<I_, 256, 0, stream>>>(out1,
        (const float*)d_in[14], (const float*)d_in[15], (const float*)d_in[16],
        (const float*)d_in[17], (const float*)d_in[18], (const float*)d_in[19],
        (const float*)d_in[20], (const float*)d_in[21], (const float*)d_in[22],
        (const float*)d_in[23], (const float*)d_in[24], (const float*)d_in[25],
        (const float*)d_in[26], (const float*)d_in[27], (const float*)d_in[28],
        (const float*)d_in[29], (const float*)d_in[30], (const float*)d_in[31],
        fct_w, fct_b, out2);
}

// Round 11
// 517.730 us; speedup vs baseline: 1.1916x; 1.1225x over previous
//
#include <hip/hip_runtime.h>
#include <hip/hip_bf16.h>
#include <cstdint>
#include <cstddef>

#define I_      100
#define J_      8
#define D_IN    768
#define D_H     64
#define N_NODES 160000
#define N_HE    320000
#define N_INC   1600000
#define N_CELLS 800
#define VOCAB   30000

#define NRANGE   256
#define NPR      625
#define EPB      (N_INC / 256)
#define SLAB     8192            // per-range bucket/csr slab (Poisson(6250), 24 sigma)

typedef unsigned short u16;
using short8 = __attribute__((ext_vector_type(8))) short;
using f32x4  = __attribute__((ext_vector_type(4))) float;

__device__ __forceinline__ float bf2f(u16 u) {
    union { uint32_t i; float f; } x; x.i = ((uint32_t)u) << 16; return x.f;
}
__device__ __forceinline__ u16 f2bf(float f) {
    union { float f; uint32_t i; } x; x.f = f;
    uint32_t b = x.i;
    b += 0x7FFFu + ((b >> 16) & 1u);
    return (u16)(b >> 16);
}
__device__ __forceinline__ float lo_bf(uint32_t u) {
    union { uint32_t i; float f; } x; x.i = u << 16; return x.f;
}
__device__ __forceinline__ float hi_bf(uint32_t u) {
    union { uint32_t i; float f; } x; x.i = u & 0xFFFF0000u; return x.f;
}
__device__ __forceinline__ uint32_t pack_bf2(float a, float b) {
    return (uint32_t)f2bf(a) | ((uint32_t)f2bf(b) << 16);
}

// grid-partition constants
#define G_OFF_HE   (N_INC / 256)        // 6250
#define G_OFF_CELL (N_NODES / 256)      // 625
#define G_CONV_BIG ((D_IN * 64) / 256)  // 192
#define G_CONV_SM  ((64 * 64) / 256)    // 16
#define G_KA       256
#define G_KB1      256
#define G_KC       256
#define G_KD       256
#define G_PGEMM    ((VOCAB + 63) / 64)  // 469  (16 rows/wave, 64 cols, 4 waves/block)
#define G_XT       (N_NODES / 64)       // 2500
#define G_X0       ((I_ * J_ + 63) / 64)// 13
#define G_HEDGE    (N_HE / 32)          // 10000 (8 hedges/wave)
#define G_NODE     (N_NODES / 32)       // 5000

// ---------------------------------------------------------------------------
__device__ __forceinline__ void dev_offsets(int bid, const int* __restrict__ sorted,
                                            int n, int nbins, int* __restrict__ off) {
    int i = bid * 256 + threadIdx.x;
    if (i >= n) return;
    int cur = sorted[i];
    int prev = (i == 0) ? -1 : sorted[i - 1];
    for (int b = prev + 1; b <= cur; ++b) off[b] = i;
    if (i == n - 1) {
        for (int b = cur + 1; b <= nbins; ++b) off[b] = n;
    }
}

__device__ __forceinline__ void dev_convT(int bid, const float* __restrict__ B,
                                          u16* __restrict__ Bt, int K) {
    int g = bid * 256 + threadIdx.x;
    if (g >= K * 64) return;
    int k = g >> 6, n = g & 63;
    Bt[(size_t)n * K + k] = f2bf(B[g]);
}

// ---------------------------------------------------------------------------
// bucket-sort CSR build (fixed slabs: no global scan, no serial chains)
// ---------------------------------------------------------------------------
// Ka: per-block histogram of node ranges
__device__ __forceinline__ void dev_ka(int bid, const int* __restrict__ inc_node,
                                       int* __restrict__ counts, int* __restrict__ lds) {
    int tid = threadIdx.x;
    lds[tid] = 0;
    __syncthreads();
    int s = bid * EPB, e = s + EPB;
    for (int i = s + tid; i < e; i += 256)
        atomicAdd(&lds[(unsigned)inc_node[i] / NPR], 1);
    __syncthreads();
    counts[bid * NRANGE + tid] = lds[tid];
}

// Kb1: one block per range-column r: LDS scan of counts[.][r]
__device__ __forceinline__ void dev_kb1(int r, const int* __restrict__ counts,
                                        int* __restrict__ chunk_off,
                                        int* __restrict__ range_total,
                                        int* __restrict__ lds) {
    int b = threadIdx.x;
    int v = counts[b * NRANGE + r];
    lds[b] = v;
    __syncthreads();
    #pragma unroll
    for (int d = 1; d < 256; d <<= 1) {
        int t = (b >= d) ? lds[b - d] : 0;
        __syncthreads();
        lds[b] += t;
        __syncthreads();
    }
    int incl = lds[b];
    chunk_off[b * NRANGE + r] = incl - v;   // exclusive prefix within column
    if (b == 255) range_total[r] = incl;
}

// Kc: scatter pairs into per-range slabs (chunk-contiguous writes)
// lds: co[256] | cur[256]
__device__ __forceinline__ void dev_kc(int bid, const int* __restrict__ inc_node,
                                       const int* __restrict__ inc_hedge,
                                       const int* __restrict__ chunk_off,
                                       int2* __restrict__ bucket, int* __restrict__ lds) {
    int tid = threadIdx.x;
    int* co  = lds;
    int* cur = lds + 256;
    co[tid]  = tid * SLAB + chunk_off[bid * NRANGE + tid];
    cur[tid] = 0;
    __syncthreads();
    int s = bid * EPB, e = s + EPB;
    for (int i = s + tid; i < e; i += 256) {
        int v = inc_node[i];
        int h = inc_hedge[i];
        int rg = (unsigned)v / NPR;
        int rank = atomicAdd(&cur[rg], 1);
        bucket[co[rg] + rank] = make_int2(v, h);
    }
}

// Kd: per-range exact CSR placement into its slab; writes node_off + node_deg
// lds layout: hist[768] | tsum[256] | cur[768]  (1792 ints)
__device__ __forceinline__ void dev_kd(int r, const int2* __restrict__ bucket,
                                       const int* __restrict__ range_total,
                                       int* __restrict__ node_off, int* __restrict__ node_deg,
                                       int* __restrict__ csr, int* __restrict__ lds) {
    int tid = threadIdx.x;
    int* hist = lds;
    int* tsum = lds + 768;
    int* cur  = lds + 1024;
    for (int i = tid; i < 768; i += 256) { hist[i] = 0; cur[i] = 0; }
    __syncthreads();
    int lo = r * NPR;
    int pb = r * SLAB;
    int pe = pb + range_total[r];
    for (int i = pb + tid; i < pe; i += 256)
        atomicAdd(&hist[bucket[i].x - lo], 1);
    __syncthreads();
    int b3 = tid * 3;
    int a0 = hist[b3], a1 = hist[b3 + 1], a2 = hist[b3 + 2];
    int s = a0 + a1 + a2;
    tsum[tid] = s;
    __syncthreads();
    #pragma unroll
    for (int d = 1; d < 256; d <<= 1) {
        int t = (tid >= d) ? tsum[tid - d] : 0;
        __syncthreads();
        tsum[tid] += t;
        __syncthreads();
    }
    int excl = tsum[tid] - s;
    hist[b3]     = excl;
    hist[b3 + 1] = excl + a0;
    hist[b3 + 2] = excl + a0 + a1;
    __syncthreads();
    for (int v = tid; v < NPR; v += 256) {
        int h0 = hist[v];
        node_off[lo + v] = pb + h0;
        node_deg[lo + v] = hist[v + 1] - h0;   // hist[625] = range total (valid)
    }
    for (int i = pb + tid; i < pe; i += 256) {
        int2 p = bucket[i];
        int l = p.x - lo;
        int k = atomicAdd(&cur[l], 1);
        csr[pb + hist[l] + k] = p.y;
    }
}

// ---------------------------------------------------------------------------
// R8 row-split barrier-free MFMA GEMM: one wave owns 16 rows x 64 cols
// ---------------------------------------------------------------------------
template <int BF16_OUT, int GATHER, int KK>
__device__ __forceinline__ void dev_gemm_direct(int wid, const float* __restrict__ A,
                                                const int* __restrict__ tok,
                                                const u16* __restrict__ Bt,
                                                const float* __restrict__ bias,
                                                void* __restrict__ C, int M) {
    int lane = threadIdx.x & 63;
    int m16 = lane & 15, q = lane >> 4;
    int base = wid << 4;
    if (base >= M) return;
    int row = base + m16;
    const float* arow = GATHER ? (A + ((size_t)tok[row] << 6))
                               : (A + (size_t)row * KK);

    f32x4 acc0 = {0.f, 0.f, 0.f, 0.f};
    f32x4 acc1 = {0.f, 0.f, 0.f, 0.f};
    f32x4 acc2 = {0.f, 0.f, 0.f, 0.f};
    f32x4 acc3 = {0.f, 0.f, 0.f, 0.f};

    #pragma unroll 2
    for (int kt = 0; kt < KK; kt += 32) {
        const float* ap = arow + kt + q * 8;
        float4 av0 = *reinterpret_cast<const float4*>(ap);
        float4 av1 = *reinterpret_cast<const float4*>(ap + 4);
        short8 a;
        a[0] = (short)f2bf(av0.x); a[1] = (short)f2bf(av0.y);
        a[2] = (short)f2bf(av0.z); a[3] = (short)f2bf(av0.w);
        a[4] = (short)f2bf(av1.x); a[5] = (short)f2bf(av1.y);
        a[6] = (short)f2bf(av1.z); a[7] = (short)f2bf(av1.w);
        const u16* bp = Bt + (size_t)m16 * KK + kt + q * 8;
        short8 b0 = *reinterpret_cast<const short8*>(bp);
        short8 b1 = *reinterpret_cast<const short8*>(bp + (size_t)16 * KK);
        short8 b2 = *reinterpret_cast<const short8*>(bp + (size_t)32 * KK);
        short8 b3 = *reinterpret_cast<const short8*>(bp + (size_t)48 * KK);
        acc0 = __builtin_amdgcn_mfma_f32_16x16x32_bf16(a, b0, acc0, 0, 0, 0);
        acc1 = __builtin_amdgcn_mfma_f32_16x16x32_bf16(a, b1, acc1, 0, 0, 0);
        acc2 = __builtin_amdgcn_mfma_f32_16x16x32_bf16(a, b2, acc2, 0, 0, 0);
        acc3 = __builtin_amdgcn_mfma_f32_16x16x32_bf16(a, b3, acc3, 0, 0, 0);
    }

    f32x4 accs[4] = {acc0, acc1, acc2, acc3};
    #pragma unroll
    for (int r = 0; r < 4; ++r) {
        int gr = base + q * 4 + r;
        #pragma unroll
        for (int j = 0; j < 4; ++j) {
            int col = j * 16 + m16;
            float v = accs[j][r];
            if (!BF16_OUT) v += bias[col];
            if (BF16_OUT)
                ((u16*)C)[(size_t)gr * 64 + col] = f2bf(v);
            else
                ((float*)C)[(size_t)gr * 64 + col] = v;
        }
    }
}

// ---------------------------------------------------------------------------
// hedge_sum: one 8-lane subgroup per hedge (8 hedges/wave)
// ---------------------------------------------------------------------------
__device__ __forceinline__ void dev_hedge_sum(int bid, const int* __restrict__ inc_node,
                                              const int* __restrict__ he_off,
                                              const u16* __restrict__ xt,
                                              u16* __restrict__ he) {
    int w = (bid * 256 + (int)threadIdx.x) >> 6;
    int lane = threadIdx.x & 63;
    int sub = lane >> 3;
    int c8 = (lane & 7) << 3;
    int hedge = w * 8 + sub;
    if (hedge >= N_HE) return;
    int s = he_off[hedge], e = he_off[hedge + 1];

    float a0 = 0.f, a1 = 0.f, a2 = 0.f, a3 = 0.f;
    float a4 = 0.f, a5 = 0.f, a6 = 0.f, a7 = 0.f;

    int idx = (s < e) ? inc_node[s] : 0;
    for (int j = s; j < e; ++j) {
        int cur = idx;
        if (j + 1 < e) idx = inc_node[j + 1];
        uint4 d = *reinterpret_cast<const uint4*>(xt + (((size_t)cur) << 6) + c8);
        a0 += lo_bf(d.x); a1 += hi_bf(d.x);
        a2 += lo_bf(d.y); a3 += hi_bf(d.y);
        a4 += lo_bf(d.z); a5 += hi_bf(d.z);
        a6 += lo_bf(d.w); a7 += hi_bf(d.w);
    }

    float inv = (e > s) ? 1.f / (float)(e - s) : 0.f;
    uint4 o;
    o.x = pack_bf2(a0 * inv, a1 * inv);
    o.y = pack_bf2(a2 * inv, a3 * inv);
    o.z = pack_bf2(a4 * inv, a5 * inv);
    o.w = pack_bf2(a6 * inv, a7 * inv);
    *reinterpret_cast<uint4*>(he + (((size_t)hedge) << 6) + c8) = o;
}

// node_sum: residual gathered from P[tok[node]]; extent via node_deg
__device__ __forceinline__ void dev_node_sum(int bid, const int* __restrict__ csr,
                                             const int* __restrict__ node_off,
                                             const int* __restrict__ node_deg,
                                             const u16* __restrict__ he,
                                             const float* __restrict__ bias,
                                             const float* __restrict__ P,
                                             const int* __restrict__ tok,
                                             float* __restrict__ out) {
    int w = (bid * 256 + (int)threadIdx.x) >> 6;
    int lane = threadIdx.x & 63;
    int sub = lane >> 3;
    int c8 = (lane & 7) << 3;
    int node = w * 8 + sub;
    if (node >= N_NODES) return;
    int s = node_off[node];
    int e = s + node_deg[node];

    float a0 = 0.f, a1 = 0.f, a2 = 0.f, a3 = 0.f;
    float a4 = 0.f, a5 = 0.f, a6 = 0.f, a7 = 0.f;

    int idx = (s < e) ? csr[s] : 0;
    for (int j = s; j < e; ++j) {
        int cur = idx;
        if (j + 1 < e) idx = csr[j + 1];
        uint4 d = *reinterpret_cast<const uint4*>(he + (((size_t)cur) << 6) + c8);
        a0 += lo_bf(d.x); a1 += hi_bf(d.x);
        a2 += lo_bf(d.y); a3 += hi_bf(d.y);
        a4 += lo_bf(d.z); a5 += hi_bf(d.z);
        a6 += lo_bf(d.w); a7 += hi_bf(d.w);
    }

    float inv = (e > s) ? 1.f / (float)(e - s) : 0.f;
    const float* nfp = P + (((size_t)tok[node]) << 6) + c8;
    float4 nv0 = *reinterpret_cast<const float4*>(nfp);
    float4 nv1 = *reinterpret_cast<const float4*>(nfp + 4);
    float4 o0, o1;
    o0.x = fmaxf(fmaf(a0, inv, bias[c8 + 0]), 0.f) + nv0.x;
    o0.y = fmaxf(fmaf(a1, inv, bias[c8 + 1]), 0.f) + nv0.y;
    o0.z = fmaxf(fmaf(a2, inv, bias[c8 + 2]), 0.f) + nv0.z;
    o0.w = fmaxf(fmaf(a3, inv, bias[c8 + 3]), 0.f) + nv0.w;
    o1.x = fmaxf(fmaf(a4, inv, bias[c8 + 4]), 0.f) + nv1.x;
    o1.y = fmaxf(fmaf(a5, inv, bias[c8 + 5]), 0.f) + nv1.y;
    o1.z = fmaxf(fmaf(a6, inv, bias[c8 + 6]), 0.f) + nv1.z;
    o1.w = fmaxf(fmaf(a7, inv, bias[c8 + 7]), 0.f) + nv1.w;
    float* op = out + (((size_t)node) << 6) + c8;
    *reinterpret_cast<float4*>(op) = o0;
    *reinterpret_cast<float4*>(op + 4) = o1;
}

// ---------------------------------------------------------------------------
// phase mega-kernels
// ---------------------------------------------------------------------------
// P0: Ka + convT x4
__global__ __launch_bounds__(256) void k_p0(const float* __restrict__ fhi_w,
                                            const float* __restrict__ fin_w,
                                            const float* __restrict__ th1,
                                            const float* __restrict__ th2,
                                            u16* __restrict__ Bt_fhi, u16* __restrict__ Bt_fin,
                                            u16* __restrict__ Bt_th1, u16* __restrict__ Bt_th2,
                                            const int* __restrict__ inc_node,
                                            int* __restrict__ counts) {
    __shared__ int lds[256];
    int bid = blockIdx.x;
    if (bid < G_KA) { dev_ka(bid, inc_node, counts, lds); return; }
    bid -= G_KA;
    if (bid < G_CONV_BIG) { dev_convT(bid, fhi_w, Bt_fhi, D_IN); return; }
    bid -= G_CONV_BIG;
    if (bid < G_CONV_BIG) { dev_convT(bid, fin_w, Bt_fin, D_IN); return; }
    bid -= G_CONV_BIG;
    if (bid < G_CONV_SM) { dev_convT(bid, th1, Bt_th1, 64); return; }
    bid -= G_CONV_SM;
    dev_convT(bid, th2, Bt_th2, 64);
}

// P1: P-GEMM + Kb1 + offsets(hedge) + offsets(cell)
__global__ __launch_bounds__(256) void k_p1(const float* __restrict__ vac_emb,
                                            const u16* __restrict__ Bt_fhi,
                                            const float* __restrict__ fhi_b, float* __restrict__ P,
                                            const int* __restrict__ counts,
                                            int* __restrict__ chunk_off, int* __restrict__ range_total,
                                            const int* __restrict__ inc_hedge,
                                            const int* __restrict__ node2cell,
                                            int* __restrict__ he_off, int* __restrict__ cell_off) {
    __shared__ int lds[256];
    int bid = blockIdx.x;
    if (bid < G_PGEMM) {
        int wid = bid * 4 + ((int)threadIdx.x >> 6);
        dev_gemm_direct<0, 0, D_IN>(wid, vac_emb, nullptr, Bt_fhi, fhi_b, P, VOCAB);
        return;
    }
    bid -= G_PGEMM;
    if (bid < G_KB1) { dev_kb1(bid, counts, chunk_off, range_total, lds); return; }
    bid -= G_KB1;
    if (bid < G_OFF_HE) { dev_offsets(bid, inc_hedge, N_INC, N_HE, he_off); return; }
    bid -= G_OFF_HE;
    dev_offsets(bid, node2cell, N_NODES, N_CELLS, cell_off);
}

// P2: xt-GEMM L1 (gather-A) + Kc + x0-GEMM
__global__ __launch_bounds__(256) void k_p2(const float* __restrict__ P,
                                            const int* __restrict__ tok,
                                            const u16* __restrict__ Bt_th1, u16* __restrict__ xt,
                                            const float* __restrict__ x, const u16* __restrict__ Bt_fin,
                                            const float* __restrict__ fin_b, float* __restrict__ x0,
                                            const int* __restrict__ inc_node,
                                            const int* __restrict__ inc_hedge,
                                            const int* __restrict__ chunk_off,
                                            int2* __restrict__ bucket) {
    __shared__ int lds[512];
    int bid = blockIdx.x;
    if (bid < G_XT) {
        int wid = bid * 4 + ((int)threadIdx.x >> 6);
        dev_gemm_direct<1, 1, 64>(wid, P, tok, Bt_th1, nullptr, xt, N_NODES);
        return;
    }
    bid -= G_XT;
    if (bid < G_KC) { dev_kc(bid, inc_node, inc_hedge, chunk_off, bucket, lds); return; }
    bid -= G_KC;
    {
        int wid = bid * 4 + ((int)threadIdx.x >> 6);
        dev_gemm_direct<0, 0, D_IN>(wid, x, nullptr, Bt_fin, fin_b, x0, I_ * J_);
    }
}

// P3: hedge_sum L1 + Kd
__global__ __launch_bounds__(256) void k_p3(const int* __restrict__ inc_node,
                                            const int* __restrict__ he_off,
                                            const u16* __restrict__ xt, u16* __restrict__ he,
                                            const int2* __restrict__ bucket,
                                            const int* __restrict__ range_total,
                                            int* __restrict__ node_off, int* __restrict__ node_deg,
                                            int* __restrict__ csr) {
    __shared__ int lds[1792];
    int bid = blockIdx.x;
    if (bid < G_HEDGE) { dev_hedge_sum(bid, inc_node, he_off, xt, he); return; }
    bid -= G_HEDGE;
    dev_kd(bid, bucket, range_total, node_off, node_deg, csr, lds);
}

// standalone wrappers
__global__ __launch_bounds__(256) void k_xt2(const float* __restrict__ A,
                                             const u16* __restrict__ Bt,
                                             u16* __restrict__ xt) {
    int wid = blockIdx.x * 4 + ((int)threadIdx.x >> 6);
    dev_gemm_direct<1, 0, 64>(wid, A, nullptr, Bt, nullptr, xt, N_NODES);
}

__global__ __launch_bounds__(256) void k_hedge_sum(const int* __restrict__ inc_node,
                                                   const int* __restrict__ he_off,
                                                   const u16* __restrict__ xt,
                                                   u16* __restrict__ he) {
    dev_hedge_sum(blockIdx.x, inc_node, he_off, xt, he);
}

__global__ __launch_bounds__(256) void k_node_sum(const int* __restrict__ csr,
                                                  const int* __restrict__ node_off,
                                                  const int* __restrict__ node_deg,
                                                  const u16* __restrict__ he,
                                                  const float* __restrict__ bias,
                                                  const float* __restrict__ P,
                                                  const int* __restrict__ tok,
                                                  float* __restrict__ out) {
    dev_node_sum(blockIdx.x, csr, node_off, node_deg, he, bias, P, tok, out);
}

// ---------------------------------------------------------------------------
__global__ __launch_bounds__(256) void k_pool(const float* __restrict__ gx,
                                              const int* __restrict__ cell_off,
                                              const float* __restrict__ x0,
                                              float* __restrict__ out1) {
    __shared__ float ssum[4][64];
    __shared__ float smax[4][64];
    int c = blockIdx.x;
    int lane = threadIdx.x & 63;
    int w = threadIdx.x >> 6;
    int s = cell_off[c], e = cell_off[c + 1];
    float sum = 0.f, mx = -INFINITY;
    for (int n = s + w; n < e; n += 4) {
        float v = gx[((size_t)n << 6) + lane];
        sum += v;
        mx = fmaxf(mx, v);
    }
    ssum[w][lane] = sum;
    smax[w][lane] = mx;
    __syncthreads();
    if (w == 0) {
        sum = ssum[0][lane] + ssum[1][lane] + ssum[2][lane] + ssum[3][lane];
        mx = fmaxf(fmaxf(smax[0][lane], smax[1][lane]), fmaxf(smax[2][lane], smax[3][lane]));
        int cnt = e - s;
        float mean = (cnt > 0) ? sum / (float)cnt : 0.f;
        float mp = (cnt > 0) ? mx : 0.f;
        float ce = 0.5f * (mean + mp);
        out1[((size_t)c << 6) + lane] = x0[((size_t)c << 6) + lane] + 0.3f * ce;
    }
}

// ---------------------------------------------------------------------------
__global__ __launch_bounds__(256) void k_tcn(
    const float* __restrict__ xu,
    const float* __restrict__ wc1, const float* __restrict__ bc1, const float* __restrict__ g1,
    const float* __restrict__ be1, const float* __restrict__ m1, const float* __restrict__ v1,
    const float* __restrict__ wc2, const float* __restrict__ bc2, const float* __restrict__ g2,
    const float* __restrict__ be2, const float* __restrict__ m2, const float* __restrict__ v2,
    const float* __restrict__ wc3, const float* __restrict__ bc3, const float* __restrict__ g3,
    const float* __restrict__ be3, const float* __restrict__ m3, const float* __restrict__ v3,
    const float* __restrict__ fct_w, const float* __restrict__ fct_b,
    float* __restrict__ out2) {
    __shared__ float w_lds[64 * 64 * 3];
    __shared__ float hA[64][10];
    __shared__ float hB[64][10];
    __shared__ float mo[64];

    int n = blockIdx.x, tid = threadIdx.x;

    if (tid < 64) {
        hA[tid][0] = 0.f; hA[tid][9] = 0.f;
        hB[tid][0] = 0.f; hB[tid][9] = 0.f;
    }
    #pragma unroll
    for (int l = tid; l < 512; l += 256) {
        int t = l >> 6, i = l & 63;
        hA[i][t + 1] = xu[(size_t)n * 512 + l];
    }

    const float* wcs[3] = {wc1, wc2, wc3};
    const float* bcs[3] = {bc1, bc2, bc3};
    const float* gs[3]  = {g1, g2, g3};
    const float* bes[3] = {be1, be2, be3};
    const float* ms[3]  = {m1, m2, m3};
    const float* vs[3]  = {v1, v2, v3};

    float (*hin)[10] = hA;
    float (*hout)[10] = hB;

    #pragma unroll
    for (int li = 0; li < 3; ++li) {
        for (int l = tid; l < 64 * 64 * 3; l += 256) w_lds[l] = wcs[li][l];
        __syncthreads();
        #pragma unroll
        for (int rep = 0; rep < 2; ++rep) {
            int idx = tid + rep * 256;
            int o = idx >> 3, t = idx & 7;
            float acc = bcs[li][o];
            #pragma unroll 8
            for (int i = 0; i < 64; ++i) {
                const float* wr = &w_lds[o * 192 + i * 3];
                acc = fmaf(hin[i][t + 0], wr[0], acc);
                acc = fmaf(hin[i][t + 1], wr[1], acc);
                acc = fmaf(hin[i][t + 2], wr[2], acc);
            }
            acc = fmaxf(acc, 0.f);
            float sc = gs[li][o] * rsqrtf(vs[li][o] + 1e-5f);
            acc = (acc - ms[li][o]) * sc + bes[li][o];
            hout[o][t + 1] = acc;
        }
        __syncthreads();
        float (*tmp)[10] = hin; hin = hout; hout = tmp;
    }

    if (tid < 64) {
        float s = 0.f;
        #pragma unroll
        for (int t = 0; t < 8; ++t) s += hin[tid][t + 1];
        mo[tid] = s * 0.125f;
    }
    __syncthreads();
    if (tid < 64) {
        float acc = fct_b[tid];
        #pragma unroll 8
        for (int o = 0; o < 64; ++o) acc = fmaf(mo[o], fct_w[o * 64 + tid], acc);
        out2[(size_t)n * 64 + tid] = acc;
    }
}

// ---------------------------------------------------------------------------
extern "C" void kernel_launch(void* const* d_in, const int* in_sizes, int n_in,
                              void* d_out, int out_size, void* d_ws, size_t ws_size,
                              hipStream_t stream) {
    (void)in_sizes; (void)n_in; (void)out_size; (void)ws_size;

    const float* x          = (const float*)d_in[0];
    const int*   node_tok   = (const int*)d_in[1];
    const int*   inc_node   = (const int*)d_in[2];
    const int*   inc_hedge  = (const int*)d_in[3];
    const int*   node2cell  = (const int*)d_in[4];
    const float* vac_emb    = (const float*)d_in[5];
    const float* fhi_w      = (const float*)d_in[6];
    const float* fhi_b      = (const float*)d_in[7];
    const float* fin_w      = (const float*)d_in[8];
    const float* fin_b      = (const float*)d_in[9];
    const float* th1        = (const float*)d_in[10];
    const float* b1         = (const float*)d_in[11];
    const float* th2        = (const float*)d_in[12];
    const float* b2         = (const float*)d_in[13];
    const float* fct_w      = (const float*)d_in[32];
    const float* fct_b      = (const float*)d_in[33];

    char* ws = (char*)d_ws;
    size_t off = 0;
    float* P        = (float*)(ws + off); off += (size_t)VOCAB * 64 * 4;
    float* hbuf     = (float*)(ws + off); off += (size_t)N_NODES * 64 * 4;
    u16*   xt       = (u16*)(ws + off);   off += (size_t)N_NODES * 64 * 2;
    u16*   he       = (u16*)(ws + off);   off += (size_t)N_HE * 64 * 2;
    int2*  bucket   = (int2*)(ws + off);  off += (size_t)NRANGE * SLAB * 8;   // 16.8 MB
    int*   csr      = (int*)(ws + off);   off += (size_t)NRANGE * SLAB * 4;   //  8.4 MB
    float* x0       = (float*)(ws + off); off += (size_t)N_CELLS * 64 * 4;
    u16*   Bt_fhi   = (u16*)(ws + off);   off += (size_t)64 * D_IN * 2;
    u16*   Bt_fin   = (u16*)(ws + off);   off += (size_t)64 * D_IN * 2;
    u16*   Bt_th1   = (u16*)(ws + off);   off += (size_t)64 * 64 * 2;
    u16*   Bt_th2   = (u16*)(ws + off);   off += (size_t)64 * 64 * 2;
    int*   he_off   = (int*)(ws + off);   off += ((size_t)(N_HE + 1) * 4 + 255) / 256 * 256;
    int*   node_off = (int*)(ws + off);   off += (size_t)N_NODES * 4;
    int*   node_deg = (int*)(ws + off);   off += (size_t)N_NODES * 4;
    int*   cell_off = (int*)(ws + off);   off += ((size_t)(N_CELLS + 1) * 4 + 255) / 256 * 256;

    // counts/chunk_off/range_total alias hbuf (all consumed by Kd in P3;
    // hbuf first written by node_sum L1 in P4)
    int*  counts      = (int*)hbuf;
    int*  chunk_off   = counts + NRANGE * NRANGE;
    int*  range_total = chunk_off + NRANGE * NRANGE;

    float* out1 = (float*)d_out;
    float* out2 = out1 + (size_t)I_ * J_ * D_H;

    // P0: Ka + convT x4
    k_p0<<<G_KA + 2 * G_CONV_BIG + 2 * G_CONV_SM, 256, 0, stream>>>(
        fhi_w, fin_w, th1, th2, Bt_fhi, Bt_fin, Bt_th1, Bt_th2, inc_node, counts);

    // P1: P-GEMM + Kb1 + offsets(hedge) + offsets(cell)
    k_p1<<<G_PGEMM + G_KB1 + G_OFF_HE + G_OFF_CELL, 256, 0, stream>>>(
        vac_emb, Bt_fhi, fhi_b, P, counts, chunk_off, range_total,
        inc_hedge, node2cell, he_off, cell_off);

    // P2: xt-GEMM L1 (gather-A) + Kc + x0-GEMM
    k_p2<<<G_XT + G_KC + G_X0, 256, 0, stream>>>(P, node_tok, Bt_th1, xt,
                                                 x, Bt_fin, fin_b, x0,
                                                 inc_node, inc_hedge, chunk_off, bucket);

    // P3: hedge_sum L1 + Kd
    k_p3<<<G_HEDGE + G_KD, 256, 0, stream>>>(inc_node, he_off, xt, he,
                                             bucket, range_total, node_off, node_deg, csr);

    // P4: node_sum L1 -> hbuf = h1
    k_node_sum<<<G_NODE, 256, 0, stream>>>(csr, node_off, node_deg, he, b1, P, node_tok, hbuf);

    // P5: xt-GEMM L2 (dense A = hbuf)
    k_xt2<<<G_XT, 256, 0, stream>>>(hbuf, Bt_th2, xt);

    // P6: hedge_sum L2
    k_hedge_sum<<<G_HEDGE, 256, 0, stream>>>(inc_node, he_off, xt, he);

    // P7: node_sum L2 -> hbuf = gx
    k_node_sum<<<G_NODE, 256, 0, stream>>>(csr, node_off, node_deg, he, b2, P, node_tok, hbuf);

    // P8: pool + fuse -> out1
    k_pool<<<N_CELLS, 256, 0, stream>>>(hbuf, cell_off, x0, out1);

    // P9: TCN -> out2
    k_tcn<<<I_, 256, 0, stream>>>(out1,
        (const float*)d_in[14], (const float*)d_in[15], (const float*)d_in[16],
        (const float*)d_in[17], (const float*)d_in[18], (const float*)d_in[19],
        (const float*)d_in[20], (const float*)d_in[21], (const float*)d_in[22],
        (const float*)d_in[23], (const float*)d_in[24], (const float*)d_in[25],
        (const float*)d_in[26], (const float*)d_in[27], (const float*)d_in[28],
        (const float*)d_in[29], (const float*)d_in[30], (const float*)d_in[31],
        fct_w, fct_b, out2);
}